// Round 9
// baseline (81.719 us; speedup 1.0000x reference)
//
#include <hip/hip_runtime.h>
#include <math.h>

#define MROWS 32768   // B*T
#define DDIM  1024
#define EDIM  64
#define NCH   64      // K-chunks of 16
#define TILEM 64      // rows per block

typedef _Float16 f16x8 __attribute__((ext_vector_type(8)));
typedef float    f32x16 __attribute__((ext_vector_type(16)));

// WS layout per chunk c (4096 halves = 8 KB), B-frag-linear (verified R4-R8):
//   half index = c*4096 + nf*512 + lane*8 + j  (+2048 for lo plane)
//   B frag (32x32x16): col = nf*32 + (lane&31), k = (lane>>5)*8 + j
//   nf: 0,1 = route col-halves; 2,3 = noise col-halves
__global__ __launch_bounds__(256)
void convW_kernel(const float* __restrict__ Wr, const float* __restrict__ Wn,
                  unsigned short* __restrict__ ws) {
    int gid = blockIdx.x * 256 + threadIdx.x;   // 131072 total
    int c32 = gid & 31;
    int j   = (gid >> 5) & 7;
    int lhi = (gid >> 8) & 1;
    int nf  = (gid >> 9) & 3;
    int c   = gid >> 11;
    int lane = lhi * 32 + c32;
    int k   = c * 16 + lhi * 8 + j;
    int col = nf * 32 + c32;                    // 0..63 route, 64..127 noise
    float w = (col < EDIM) ? Wr[k * EDIM + col] : Wn[k * EDIM + (col - EDIM)];
    _Float16 hi = (_Float16)w;
    _Float16 lo = (_Float16)((w - (float)hi) * 2048.0f);
    union { _Float16 h; unsigned short u; } cv;
    size_t base = (size_t)c * 4096 + nf * 512 + lane * 8 + j;
    cv.h = hi; ws[base]        = cv.u;
    cv.h = lo; ws[base + 2048] = cv.u;
}

__global__ __launch_bounds__(256)
void router_mfma(const float* __restrict__ X,
                 const unsigned short* __restrict__ WS,
                 const float* __restrict__ br_g,
                 const float* __restrict__ bn_g,
                 const float* __restrict__ U,
                 float* __restrict__ out)
{
    // GEMM phase: 4-buffer B ring (4 x 8 KB). Epilogue reuses as Lf[64][128] f32.
    __shared__ alignas(16) unsigned char smem[32768];

    const int t    = threadIdx.x;
    const int lane = t & 63;
    const int wid  = t >> 6;
    const int wm   = wid >> 1;    // row-group 0/1 (rows wm*32..+31)
    const int wn   = wid & 1;     // col-half 0/1
    const int rowBase = blockIdx.x * TILEM;
    const int myRow = rowBase + wm * 32 + (lane & 31);
    const int kSub  = (lane >> 5) * 8;
    const float* xp = X + (size_t)myRow * DDIM + kSub;
    const char* wsB = (const char*)WS;

    f32x16 aR0, aR1, aN0, aN1;
#pragma unroll
    for (int i = 0; i < 16; ++i) { aR0[i] = 0.f; aR1[i] = 0.f; aN0[i] = 0.f; aN1[i] = 0.f; }

    // stage chunk c (8 KB) into ring buffer `buf`: 2 DMA ops per wave
    auto stage = [&](int c, int buf) {
        const char* src = wsB + (size_t)c * 8192 + wid * 2048 + lane * 16;
        char* dst = (char*)smem + buf * 8192 + wid * 2048 + lane * 16;
        __builtin_amdgcn_global_load_lds(
            (const __attribute__((address_space(1))) void*)src,
            (__attribute__((address_space(3))) void*)dst, 16, 0, 0);
        __builtin_amdgcn_global_load_lds(
            (const __attribute__((address_space(1))) void*)(src + 1024),
            (__attribute__((address_space(3))) void*)(dst + 1024), 16, 0, 0);
    };

    auto compute = [&](const unsigned short* bc, const float4& x0, const float4& x1) {
        f16x8 ahi, alo;
        float xs[8] = {x0.x, x0.y, x0.z, x0.w, x1.x, x1.y, x1.z, x1.w};
#pragma unroll
        for (int j = 0; j < 8; ++j) {
            _Float16 h = (_Float16)xs[j];
            ahi[j] = h;
            alo[j] = (_Float16)((xs[j] - (float)h) * 2048.0f);
        }
        const unsigned short* p = bc + wn * 512 + lane * 8;
        f16x8 bhiR = *(const f16x8*)(p);
        f16x8 bhiN = *(const f16x8*)(p + 1024);
        f16x8 bloR = *(const f16x8*)(p + 2048);
        f16x8 bloN = *(const f16x8*)(p + 3072);
        aR0 = __builtin_amdgcn_mfma_f32_32x32x16_f16(ahi, bhiR, aR0, 0, 0, 0);
        aR1 = __builtin_amdgcn_mfma_f32_32x32x16_f16(ahi, bloR, aR1, 0, 0, 0);
        aR1 = __builtin_amdgcn_mfma_f32_32x32x16_f16(alo, bhiR, aR1, 0, 0, 0);
        aN0 = __builtin_amdgcn_mfma_f32_32x32x16_f16(ahi, bhiN, aN0, 0, 0, 0);
        aN1 = __builtin_amdgcn_mfma_f32_32x32x16_f16(ahi, bloN, aN1, 0, 0, 0);
        aN1 = __builtin_amdgcn_mfma_f32_32x32x16_f16(alo, bhiN, aN1, 0, 0, 0);
    };

    // ---- prologue: {S0,X0,S1,X1} = 8 outstanding vmem ops ----
    float4 x0[4], x1[4];
    stage(0, 0);
    x0[0] = *(const float4*)(xp);      x1[0] = *(const float4*)(xp + 4);
    stage(1, 1);
    x0[1] = *(const float4*)(xp + 16); x1[1] = *(const float4*)(xp + 20);

    // Per phase: issue {stage(c+2), loadX(c+2)} -> vmcnt(8) retires chunk c's
    // 4 ops exactly (chunks c+1,c+2 = 8 stay in flight) -> compute(c) ->
    // raw s_barrier (no drain). Buffer write-after-read lag = 2 barriers.
    // Tail stays uniform via harmless dummy wrap (&63 / ring slot).
#define PHASE(it, p)                                                        \
    {                                                                       \
        const int c  = (it) * 4 + (p);                                      \
        const int cn = (c + 2) & 63;                                        \
        stage(cn, ((p) + 2) & 3);                                           \
        x0[((p) + 2) & 3] = *(const float4*)(xp + cn * 16);                 \
        x1[((p) + 2) & 3] = *(const float4*)(xp + cn * 16 + 4);             \
        asm volatile("s_waitcnt vmcnt(8)" ::: "memory");                    \
        __builtin_amdgcn_sched_barrier(0);                                  \
        compute((const unsigned short*)(smem + (p) * 8192), x0[(p)], x1[(p)]); \
        __builtin_amdgcn_sched_barrier(0);                                  \
        __builtin_amdgcn_s_barrier();                                       \
    }

    for (int it = 0; it < 16; ++it) {
        PHASE(it, 0); PHASE(it, 1); PHASE(it, 2); PHASE(it, 3);
    }
#undef PHASE

    __syncthreads();   // full drain (incl. dummy DMAs) before smem reuse

    // ---- epilogue: combine hi/lo, logits tile to LDS ----
    float* Lf = (float*)smem;   // Lf[64][128]
    const float inv2048 = 1.0f / 2048.0f;
    {
        const int colR = wn * 32 + (lane & 31);
#pragma unroll
        for (int reg = 0; reg < 16; ++reg) {
            int rl  = (reg & 3) + 8 * (reg >> 2) + 4 * (lane >> 5);
            int row = wm * 32 + rl;
            Lf[row * 128 + colR]      = aR0[reg] + aR1[reg] * inv2048;
            Lf[row * 128 + 64 + colR] = aN0[reg] + aN1[reg] * inv2048;
        }
    }
    __syncthreads();

    // ---- bias + softplus-noise + two-pass butterfly top-2 + writes ----
    const float brv = br_g[lane];
    const float bnv = bn_g[lane];
#pragma unroll 4
    for (int r = 0; r < 16; ++r) {
        int row  = wid * 16 + r;
        int grow = rowBase + row;
        float lr = Lf[row * 128 + lane] + brv;
        float ln = Lf[row * 128 + 64 + lane] + bnv;
        float u  = U[(size_t)grow * EDIM + lane];
        float noisy = lr + u * log1pf(expf(ln));

        // pass 1: argmax with lowest-index tie-break
        float m1 = noisy; int i1 = lane;
#pragma unroll
        for (int s = 1; s < 64; s <<= 1) {
            float om = __shfl_xor(m1, s);
            int   oi = __shfl_xor(i1, s);
            if (om > m1 || (om == m1 && oi < i1)) { m1 = om; i1 = oi; }
        }
        // pass 2: argmax excluding i1
        float m2 = (lane == i1) ? -INFINITY : noisy;
        int   i2 = lane;
#pragma unroll
        for (int s = 1; s < 64; s <<= 1) {
            float om = __shfl_xor(m2, s);
            int   oi = __shfl_xor(i2, s);
            if (om > m2 || (om == m2 && oi < i2)) { m2 = om; i2 = oi; }
        }

        float e2  = expf(m2 - m1);
        float inv = 1.0f / (1.0f + e2);
        float p   = (lane == i1) ? inv : ((lane == i2) ? e2 * inv : 0.0f);
        out[(size_t)grow * EDIM + lane] = p;
        if (lane < 2)
            out[(size_t)MROWS * EDIM + (size_t)grow * 2 + lane] =
                (float)(lane == 0 ? i1 : i2);
    }
}

extern "C" void kernel_launch(void* const* d_in, const int* in_sizes, int n_in,
                              void* d_out, int out_size, void* d_ws, size_t ws_size,
                              hipStream_t stream) {
    const float* X  = (const float*)d_in[0];  // mh_output [8,4096,1024]
    const float* Wr = (const float*)d_in[1];  // W_route   [1024,64]
    const float* br = (const float*)d_in[2];  // b_route   [64]
    const float* Wn = (const float*)d_in[3];  // W_noise   [1024,64]
    const float* bn = (const float*)d_in[4];  // b_noise   [64]
    const float* U  = (const float*)d_in[5];  // noise_u   [8,4096,64]
    (void)in_sizes; (void)n_in; (void)ws_size; // uses 512 KB of d_ws
    unsigned short* ws16 = (unsigned short*)d_ws;
    convW_kernel<<<512, 256, 0, stream>>>(Wr, Wn, ws16);
    router_mfma<<<MROWS / TILEM, 256, 0, stream>>>(X, ws16, br, bn, U, (float*)d_out);
}

// Round 11
// 62.228 us; speedup vs baseline: 1.3132x; 1.3132x over previous
//
#include <hip/hip_runtime.h>
#include <math.h>

#define MROWS 32768   // B*T
#define DDIM  1024
#define EDIM  64
#define NCH   64      // K-chunks of 16
#define TILEM 32      // rows per block; grid = 1024 -> 4 blocks/CU

typedef _Float16 f16x8 __attribute__((ext_vector_type(8)));
typedef float    f32x16 __attribute__((ext_vector_type(16)));

// WS layout per chunk c (4096 halves = 8 KB), B-frag-linear (verified R4-R9):
//   half index = c*4096 + nf*512 + lane*8 + j  (+2048 for lo plane)
//   B frag (32x32x16): col = nf*32 + (lane&31), k = (lane>>5)*8 + j
//   nf: 0,1 = route col-halves; 2,3 = noise col-halves
__global__ __launch_bounds__(256)
void convW_kernel(const float* __restrict__ Wr, const float* __restrict__ Wn,
                  unsigned short* __restrict__ ws) {
    int gid = blockIdx.x * 256 + threadIdx.x;   // 131072 total
    int c32 = gid & 31;
    int j   = (gid >> 5) & 7;
    int lhi = (gid >> 8) & 1;
    int nf  = (gid >> 9) & 3;
    int c   = gid >> 11;
    int lane = lhi * 32 + c32;
    int k   = c * 16 + lhi * 8 + j;
    int col = nf * 32 + c32;                    // 0..63 route, 64..127 noise
    float w = (col < EDIM) ? Wr[k * EDIM + col] : Wn[k * EDIM + (col - EDIM)];
    _Float16 hi = (_Float16)w;
    _Float16 lo = (_Float16)((w - (float)hi) * 2048.0f);
    union { _Float16 h; unsigned short u; } cv;
    size_t base = (size_t)c * 4096 + nf * 512 + lane * 8 + j;
    cv.h = hi; ws[base]        = cv.u;
    cv.h = lo; ws[base + 2048] = cv.u;
}

__global__ __launch_bounds__(256, 4)
void router_mfma(const float* __restrict__ X,
                 const unsigned short* __restrict__ WS,
                 const float* __restrict__ br_g,
                 const float* __restrict__ bn_g,
                 const float* __restrict__ U,
                 float* __restrict__ out)
{
    // GEMM: Ah [2buf][2p][32][24] halves (6144 B) | Bh [2buf][4096] halves (16384 B)
    // Epilogue union: Lf[32][132] f32 (16896 B)
    __shared__ alignas(16) unsigned char smem[22528];
    unsigned short* Ah = (unsigned short*)smem;
    unsigned short* Bh = (unsigned short*)(smem + 6144);
    float*          Lf = (float*)smem;

    const int t    = threadIdx.x;
    const int lane = t & 63;
    const int wid  = t >> 6;                  // 0..3: nf group (B-col group)
    const int rowBase = blockIdx.x * TILEM;
    const int start   = (blockIdx.x & 7) * 8; // chunk-order rotation (de-convoy WS)

    // A staging map: thread -> (row, 2 consecutive k)
    const int arow = t >> 3;        // 0..31
    const int akk  = (t & 7) * 2;   // 0,2,..,14
    const float* xbase = X + (size_t)(rowBase + arow) * DDIM + akk;

    f32x16 acc0, acc1;
#pragma unroll
    for (int i = 0; i < 16; ++i) { acc0[i] = 0.f; acc1[i] = 0.f; }

    auto stageB = [&](int c, int buf) {   // 2 x 1 KB DMA per wave = full 8 KB/chunk
        const char* src = (const char*)WS + (size_t)c * 8192 + wid * 2048 + lane * 16;
        char* dst = (char*)(smem + 6144) + buf * 8192 + wid * 2048 + lane * 16;
        __builtin_amdgcn_global_load_lds(
            (const __attribute__((address_space(1))) void*)src,
            (__attribute__((address_space(3))) void*)dst, 16, 0, 0);
        __builtin_amdgcn_global_load_lds(
            (const __attribute__((address_space(1))) void*)(src + 1024),
            (__attribute__((address_space(3))) void*)(dst + 1024), 16, 0, 0);
    };

    auto convA = [&](float2 xv, int buf) {  // 2 elems/thread -> hi/lo planes
        _Float16 h0 = (_Float16)xv.x;
        _Float16 h1 = (_Float16)xv.y;
        _Float16 l0 = (_Float16)((xv.x - (float)h0) * 2048.0f);
        _Float16 l1 = (_Float16)((xv.y - (float)h1) * 2048.0f);
        union { _Float16 h[2]; unsigned int u; } ph, pl;
        ph.h[0] = h0; ph.h[1] = h1; pl.h[0] = l0; pl.h[1] = l1;
        *(unsigned int*)(Ah + ((buf * 2 + 0) * 32 + arow) * 24 + akk) = ph.u;
        *(unsigned int*)(Ah + ((buf * 2 + 1) * 32 + arow) * 24 + akk) = pl.u;
    };

    auto compute = [&](int buf) {           // 3 MFMA per wave per chunk
        const unsigned short* Ab = Ah + (buf * 2) * 768;   // 32*24 = 768
        const int aoff = (lane & 31) * 24 + (lane >> 5) * 8;
        f16x8 ahi = *(const f16x8*)(Ab + aoff);
        f16x8 alo = *(const f16x8*)(Ab + 768 + aoff);
        const unsigned short* Bb = Bh + buf * 4096 + wid * 512 + lane * 8;
        f16x8 bhi = *(const f16x8*)(Bb);
        f16x8 blo = *(const f16x8*)(Bb + 2048);
        acc0 = __builtin_amdgcn_mfma_f32_32x32x16_f16(ahi, bhi, acc0, 0, 0, 0);
        acc1 = __builtin_amdgcn_mfma_f32_32x32x16_f16(ahi, blo, acc1, 0, 0, 0);
        acc1 = __builtin_amdgcn_mfma_f32_32x32x16_f16(alo, bhi, acc1, 0, 0, 0);
    };

    // ---- prologue: chunk `start` in buf0; X pipeline 2 deep ----
    float2 xA = *(const float2*)(xbase + (size_t)start * 16);
    stageB(start, 0);
    convA(xA, 0);
    xA = *(const float2*)(xbase + (size_t)((start + 1) & 63) * 16);
    float2 xB = *(const float2*)(xbase + (size_t)((start + 2) & 63) * 16);
    __syncthreads();

    // phase i: stage c(i+1)->buf^1 | issue x-load c(i+3) | compute buf |
    //          convA c(i+1) -> buf^1 | barrier.  (CUR holds c(i+1), NXT c(i+2))
#define PHASE(I, CUR, NXT)                                                     \
    {                                                                          \
        const int buf = (I) & 1;                                               \
        if ((I) + 1 < NCH) stageB((start + (I) + 1) & 63, buf ^ 1);            \
        float2 tmp = CUR;                                                      \
        if ((I) + 3 < NCH)                                                     \
            tmp = *(const float2*)(xbase + (size_t)((start + (I) + 3) & 63) * 16); \
        compute(buf);                                                          \
        if ((I) + 1 < NCH) convA(CUR, buf ^ 1);                                \
        CUR = tmp;                                                             \
        __syncthreads();                                                       \
    }

    for (int i = 0; i < NCH; i += 2) {
        PHASE(i,     xA, xB);
        PHASE(i + 1, xB, xA);
    }
#undef PHASE

    // ---- epilogue: combine hi/lo, logits tile into LDS ----
    const float inv2048 = 1.0f / 2048.0f;
    const int lcol = wid * 32 + (lane & 31);   // 0..63 route, 64..127 noise
#pragma unroll
    for (int reg = 0; reg < 16; ++reg) {
        int r = (reg & 3) + 8 * (reg >> 2) + 4 * (lane >> 5);
        Lf[r * 132 + lcol] = acc0[reg] + acc1[reg] * inv2048;
    }
    __syncthreads();

    // ---- bias + softplus-noise + butterfly top-2 + writes (8 rows/wave) ----
    const float brv = br_g[lane];
    const float bnv = bn_g[lane];
#pragma unroll 2
    for (int r8 = 0; r8 < 8; ++r8) {
        int lrow = wid * 8 + r8;
        int grow = rowBase + lrow;
        float lr = Lf[lrow * 132 + lane] + brv;
        float ln = Lf[lrow * 132 + 64 + lane] + bnv;
        float u  = U[(size_t)grow * EDIM + lane];
        float noisy = lr + u * log1pf(expf(ln));

        float m1 = noisy; int i1 = lane;
        float m2 = -INFINITY; int i2 = 64;
#pragma unroll
        for (int s = 1; s < 64; s <<= 1) {
            float om1 = __shfl_xor(m1, s); int oi1 = __shfl_xor(i1, s);
            float om2 = __shfl_xor(m2, s); int oi2 = __shfl_xor(i2, s);
            bool aw = (m1 > om1) || (m1 == om1 && i1 < oi1);
            float w1  = aw ? m1 : om1;  int wi1  = aw ? i1 : oi1;
            float c2a = aw ? m2 : om2;  int c2ai = aw ? i2 : oi2;
            float c2b = aw ? om1 : m1;  int c2bi = aw ? oi1 : i1;
            bool bw = (c2b > c2a) || (c2b == c2a && c2bi < c2ai);
            m1 = w1; i1 = wi1;
            m2 = bw ? c2b : c2a;
            i2 = bw ? c2bi : c2ai;
        }
        float e2  = expf(m2 - m1);
        float inv = 1.0f / (1.0f + e2);
        float p   = (lane == i1) ? inv : ((lane == i2) ? e2 * inv : 0.0f);
        out[(size_t)grow * EDIM + lane] = p;
        if (lane < 2)
            out[(size_t)MROWS * EDIM + (size_t)grow * 2 + lane] =
                (float)(lane == 0 ? i1 : i2);
    }
}

extern "C" void kernel_launch(void* const* d_in, const int* in_sizes, int n_in,
                              void* d_out, int out_size, void* d_ws, size_t ws_size,
                              hipStream_t stream) {
    const float* X  = (const float*)d_in[0];  // mh_output [8,4096,1024]
    const float* Wr = (const float*)d_in[1];  // W_route   [1024,64]
    const float* br = (const float*)d_in[2];  // b_route   [64]
    const float* Wn = (const float*)d_in[3];  // W_noise   [1024,64]
    const float* bn = (const float*)d_in[4];  // b_noise   [64]
    const float* U  = (const float*)d_in[5];  // noise_u   [8,4096,64]
    (void)in_sizes; (void)n_in; (void)ws_size; // uses 512 KB of d_ws
    unsigned short* ws16 = (unsigned short*)d_ws;
    convW_kernel<<<512, 256, 0, stream>>>(Wr, Wn, ws16);
    router_mfma<<<MROWS / TILEM, 256, 0, stream>>>(X, ws16, br, bn, U, (float*)d_out);
}